// Round 6
// baseline (1946.515 us; speedup 1.0000x reference)
//
#include <hip/hip_runtime.h>
#include <hip/hip_bf16.h>
#include <stdint.h>

typedef float f32x4 __attribute__((ext_vector_type(4)));
typedef short bf16x8 __attribute__((ext_vector_type(8)));

__device__ __forceinline__ ushort to_bf16(float f) {
    union { float f; uint32_t u; } v; v.f = f;
    uint32_t u = v.u;
    return (ushort)((u + 0x7fffu + ((u >> 16) & 1u)) >> 16);   // RNE
}
__device__ __forceinline__ float sigmoid_(float x) { return 1.0f / (1.0f + __expf(-x)); }
__device__ __forceinline__ float tanh_(float x)    { return 1.0f - 2.0f / (__expf(2.0f * x) + 1.0f); }

// Swizzled concat weight W'[g][k] = (k<384 ? w_ih : w_hh), bf16; fragment layout:
// elem ((tile*24 + kc)*64 + quad*16 + (g&15))*8 + j  for k = kc*32 + quad*8 + j
__global__ void prep_w(const float* __restrict__ w_ih, const float* __restrict__ w_hh,
                       ushort* __restrict__ wswz) {
    int tid = blockIdx.x * blockDim.x + threadIdx.x;   // 1152 * 96
    if (tid >= 1152 * 96) return;
    int g  = tid / 96;
    int k  = (tid % 96) * 8;
    int kc = k >> 5;
    int q  = (k >> 3) & 3;
    int tile = g >> 4;
    int lane = q * 16 + (g & 15);
    ushort* dst = wswz + ((size_t)(tile * 24 + kc) * 64 + lane) * 8;
    const float* src = (k < 384) ? (w_ih + (size_t)g * 384 + k)
                                 : (w_hh + (size_t)g * 384 + (k - 384));
#pragma unroll
    for (int j = 0; j < 8; ++j) dst[j] = to_bf16(src[j]);
}

__global__ void embed_gather(const int* __restrict__ tok, const float* __restrict__ table,
                             ushort* __restrict__ xleaf, int n_leaves) {
    int tid = blockIdx.x * blockDim.x + threadIdx.x;   // n_leaves * 48
    if (tid >= n_leaves * 48) return;
    int leaf = tid / 48, i = tid % 48;
    const float* src = table + (size_t)tok[leaf] * 384 + i * 8;
    bf16x8 v;
#pragma unroll
    for (int j = 0; j < 8; ++j) v[j] = (short)to_bf16(src[j]);
    *(bf16x8*)(xleaf + (size_t)leaf * 384 + i * 8) = v;
}

struct TreeParams {
    const ushort* XA;          // leaf x, bf16 [32768*384]
    const ushort* W;           // swizzled weights
    const float* bih;
    const float* bhh;
    float* fout;               // d_out [384]
    ushort* HB[5];             // bf16 h slots 0..7   [8*P*384]
    float*  HT[5];             // f32  h slots 0..7   [8*P*384]
    ushort* Xo[5];             // level outputs, bf16 [P*384]
    unsigned int* ctr;         // barrier counters (zeroed)
};

// Device-scope barrier among `target` blocks on a dedicated (never-reused) counter.
// __threadfence() provides agent-scope release/acquire (L2 writeback + invalidate),
// so correctness does NOT depend on which XCD a block landed on.
__device__ __forceinline__ void barrier_dev(unsigned int* c, unsigned int target) {
    __syncthreads();
    if (threadIdx.x == 0) {
        __threadfence();
        __hip_atomic_fetch_add(c, 1u, __ATOMIC_RELEASE, __HIP_MEMORY_SCOPE_AGENT);
        while (__hip_atomic_load(c, __ATOMIC_ACQUIRE, __HIP_MEMORY_SCOPE_AGENT) < target)
            __builtin_amdgcn_s_sleep(2);
        __threadfence();
    }
    __syncthreads();
}

#define MFMA(a, b, c) __builtin_amdgcn_mfma_f32_16x16x32_bf16((a), (b), (c), 0, 0, 0)

// One persistent kernel for the whole tree. Grid (16 m-groups, 12 ds-slices) = 192
// blocks, 1 block/CU (147 KB LDS) -> all co-resident. Block (bx, ds) owns dims
// ds*32..+31 (gate triples r,z,n -> GRU update lane-local) for rows of group bx.
// Wave w handles m-tiles ti = bx*16 + i*4 + w, i=0..3 (64 rows); every B fragment
// (from LDS) feeds 4 MFMAs. Within-level steps: 12-block/group atomic barrier;
// level transitions: 192-block global barrier. Parent h0 = mean of children h8,
// computed at child last step via shfl quad-pair reduction.
__global__ __launch_bounds__(256, 1)
void tree_kernel(TreeParams p) {
    __shared__ ushort LW[6 * 12288];   // [slot s][kc][lane*8]; s = gate*2 + j
    const int tid = threadIdx.x;
    const int wave = tid >> 6, lane = tid & 63;
    const int quad = lane >> 4, col = lane & 15;
    const int bx = blockIdx.x, ds = blockIdx.y;

    // Stage this block's 6 weight tiles into LDS once (then never re-read).
#pragma unroll
    for (int s = 0; s < 6; ++s) {
        const int gsrc = (s >> 1) * 24 + 2 * ds + (s & 1);
        const uint4* src = (const uint4*)(p.W + (size_t)gsrc * 12288);
        uint4* dst = (uint4*)(LW + s * 12288);
        for (int c = tid; c < 1536; c += 256) dst[c] = src[c];
    }

    int dj[2]; float br[2], bz[2], bi[2], bh2[2];
#pragma unroll
    for (int j = 0; j < 2; ++j) {
        dj[j] = ds * 32 + j * 16 + col;
        br[j] = p.bih[dj[j]] + p.bhh[dj[j]];
        bz[j] = p.bih[384 + dj[j]] + p.bhh[384 + dj[j]];
        bi[j] = p.bih[768 + dj[j]];
        bh2[j] = p.bhh[768 + dj[j]];
    }
    __syncthreads();

    const int Ps[5] = {4096, 512, 64, 8, 1};
    const bf16x8 zf = {0, 0, 0, 0, 0, 0, 0, 0};
    const f32x4 z4 = {0.f, 0.f, 0.f, 0.f};

    for (int lv = 0; lv < 5; ++lv) {
        const int P = Ps[lv];
        const int nTiles = (P + 15) >> 4;
        const int nGroups = (nTiles + 15) >> 4;
        const size_t N = (size_t)P * 384;
        const ushort* Xc = (lv == 0) ? p.XA : p.Xo[lv - 1];
        ushort* HB = p.HB[lv];
        float*  HT = p.HT[lv];
        ushort* Xo = p.Xo[lv];

        if (bx < nGroups) {
            int ti[4], par[4]; bool tv[4], av[4];
#pragma unroll
            for (int i = 0; i < 4; ++i) {
                ti[i] = bx * 16 + i * 4 + wave;
                tv[i] = ti[i] < nTiles;
                par[i] = ti[i] * 16 + col;
                av[i] = tv[i] && (par[i] < P);
            }

            for (int t = 0; t < 8; ++t) {
                if (t) barrier_dev(&p.ctr[(lv * 7 + (t - 1)) * 16 + bx], 12u);
                const int child = 7 - t;
                const bool hz = (lv == 0 && t == 0);
                const ushort* HBp = HB + (size_t)t * N;
                const float*  HTp = HT + (size_t)t * N;

                // previous h (f32 master) for the z-blend
                float hp[2][4][4];
#pragma unroll
                for (int j = 0; j < 2; ++j)
#pragma unroll
                    for (int i = 0; i < 4; ++i)
#pragma unroll
                        for (int r = 0; r < 4; ++r) {
                            const int m = ti[i] * 16 + quad * 4 + r;
                            hp[j][i][r] = (!hz && tv[i] && m < P)
                                              ? HTp[(size_t)m * 384 + dj[j]] : 0.0f;
                        }

                f32x4 ar[2][4], az[2][4], an1[2][4], an2[2][4];
#pragma unroll
                for (int j = 0; j < 2; ++j)
#pragma unroll
                    for (int i = 0; i < 4; ++i) {
                        ar[j][i] = z4; az[j][i] = z4; an1[j][i] = z4; an2[j][i] = z4;
                    }

                // x half (W_ih columns, kc 0..11)
#pragma unroll
                for (int kc = 0; kc < 12; ++kc) {
                    bf16x8 a[4];
#pragma unroll
                    for (int i = 0; i < 4; ++i)
                        a[i] = av[i] ? *(const bf16x8*)(Xc + ((size_t)par[i] * 8 + child) * 384
                                                        + kc * 32 + quad * 8)
                                     : zf;
#pragma unroll
                    for (int j = 0; j < 2; ++j) {
                        const bf16x8 bR = *(const bf16x8*)(LW + ((0 + j) * 24 + kc) * 512 + lane * 8);
                        const bf16x8 bZ = *(const bf16x8*)(LW + ((2 + j) * 24 + kc) * 512 + lane * 8);
                        const bf16x8 bN = *(const bf16x8*)(LW + ((4 + j) * 24 + kc) * 512 + lane * 8);
#pragma unroll
                        for (int i = 0; i < 4; ++i) {
                            ar[j][i]  = MFMA(a[i], bR, ar[j][i]);
                            az[j][i]  = MFMA(a[i], bZ, az[j][i]);
                            an1[j][i] = MFMA(a[i], bN, an1[j][i]);
                        }
                    }
                }
                // h half (W_hh columns, kc 12..23) — skipped when h == 0
                if (!hz) {
#pragma unroll
                    for (int kc = 0; kc < 12; ++kc) {
                        bf16x8 a[4];
#pragma unroll
                        for (int i = 0; i < 4; ++i)
                            a[i] = av[i] ? *(const bf16x8*)(HBp + (size_t)par[i] * 384
                                                            + kc * 32 + quad * 8)
                                         : zf;
#pragma unroll
                        for (int j = 0; j < 2; ++j) {
                            const bf16x8 bR = *(const bf16x8*)(LW + ((0 + j) * 24 + 12 + kc) * 512 + lane * 8);
                            const bf16x8 bZ = *(const bf16x8*)(LW + ((2 + j) * 24 + 12 + kc) * 512 + lane * 8);
                            const bf16x8 bN = *(const bf16x8*)(LW + ((4 + j) * 24 + 12 + kc) * 512 + lane * 8);
#pragma unroll
                            for (int i = 0; i < 4; ++i) {
                                ar[j][i]  = MFMA(a[i], bR, ar[j][i]);
                                az[j][i]  = MFMA(a[i], bZ, az[j][i]);
                                an2[j][i] = MFMA(a[i], bN, an2[j][i]);
                            }
                        }
                    }
                }

                // epilogue: GRU update (lane-local: block owns r,z,n for its dims)
                float hnv[2][4][4];
#pragma unroll
                for (int j = 0; j < 2; ++j)
#pragma unroll
                    for (int i = 0; i < 4; ++i)
#pragma unroll
                        for (int r = 0; r < 4; ++r) {
                            hnv[j][i][r] = 0.0f;
                            const int m = ti[i] * 16 + quad * 4 + r;
                            if (tv[i] && m < P) {
                                const size_t idx = (size_t)m * 384 + dj[j];
                                const float rv = sigmoid_(ar[j][i][r] + br[j]);
                                const float zv = sigmoid_(az[j][i][r] + bz[j]);
                                const float nv = tanh_(an1[j][i][r] + bi[j]
                                                       + rv * (an2[j][i][r] + bh2[j]));
                                const float hn = (1.0f - zv) * nv + zv * hp[j][i][r];
                                hnv[j][i][r] = hn;
                                if (t < 7) {
                                    HT[(size_t)(t + 1) * N + idx] = hn;
                                    HB[(size_t)(t + 1) * N + idx] = to_bf16(hn);
                                } else {
                                    // node output = mean(h1..h8) = (h1..h6 + hp(=h7) + hn)/8
                                    float xs = hn + hp[j][i][r];
#pragma unroll
                                    for (int s = 1; s <= 6; ++s) xs += HT[(size_t)s * N + idx];
                                    const float xo = xs * 0.125f;
                                    Xo[idx] = to_bf16(xo);
                                    if (lv == 4 && m == 0) p.fout[dj[j]] = xo;
                                }
                            }
                        }

                // at last step: emit parent h0 = mean of 8 children h8 (shfl quad-pairs)
                if (t == 7 && lv < 4) {
                    const int Pn = Ps[lv + 1];
                    float*  HTn = p.HT[lv + 1];
                    ushort* HBn = p.HB[lv + 1];
#pragma unroll
                    for (int j = 0; j < 2; ++j)
#pragma unroll
                        for (int i = 0; i < 4; ++i) {
                            if (!tv[i]) continue;
                            const float s4 = hnv[j][i][0] + hnv[j][i][1]
                                           + hnv[j][i][2] + hnv[j][i][3];
                            const float o = __shfl_xor(s4, 16, 64);   // pair quads (0,1),(2,3)
                            if ((quad & 1) == 0) {
                                const int pnode = 2 * ti[i] + (quad >> 1);
                                if (pnode < Pn) {
                                    const float h0 = (s4 + o) * 0.125f;
                                    HTn[(size_t)pnode * 384 + dj[j]] = h0;
                                    HBn[(size_t)pnode * 384 + dj[j]] = to_bf16(h0);
                                }
                            }
                        }
                }
            }
        }

        if (lv < 4) barrier_dev(&p.ctr[560 + lv], 192u);
    }
}

extern "C" void kernel_launch(void* const* d_in, const int* in_sizes, int n_in,
                              void* d_out, int out_size, void* d_ws, size_t ws_size,
                              hipStream_t stream) {
    const int*   tok   = (const int*)d_in[0];
    const float* table = (const float*)d_in[1];
    const float* w_ih  = (const float*)d_in[2];
    const float* w_hh  = (const float*)d_in[3];
    const float* b_ih  = (const float*)d_in[4];
    const float* b_hh  = (const float*)d_in[5];
    float* out = (float*)d_out;

    char* ws = (char*)d_ws;
    size_t off = 0;
    auto alloc = [&](size_t bytes) -> void* {
        void* p = ws + off;
        off = (off + bytes + 255) & ~(size_t)255;
        return p;
    };
    ushort* wswz = (ushort*)alloc((size_t)1152 * 768 * 2);
    ushort* XA   = (ushort*)alloc((size_t)32768 * 384 * 2);

    TreeParams tp;
    tp.XA = XA; tp.W = wswz; tp.bih = b_ih; tp.bhh = b_hh; tp.fout = out;
    const int Ps[5] = {4096, 512, 64, 8, 1};
    for (int lv = 0; lv < 5; ++lv) {
        size_t N = (size_t)Ps[lv] * 384;
        tp.HT[lv] = (float*) alloc(8 * N * 4);
        tp.HB[lv] = (ushort*)alloc(8 * N * 2);
        tp.Xo[lv] = (ushort*)alloc(N * 2);
    }
    tp.ctr = (unsigned int*)alloc(1024 * 4);

    hipMemsetAsync(tp.ctr, 0, 1024 * 4, stream);
    prep_w<<<(1152 * 96 + 255) / 256, 256, 0, stream>>>(w_ih, w_hh, wswz);
    embed_gather<<<(32768 * 48 + 255) / 256, 256, 0, stream>>>(tok, table, XA, 32768);

    tree_kernel<<<dim3(16, 12), 256, 0, stream>>>(tp);
}